// Round 1
// baseline (35571.326 us; speedup 1.0000x reference)
//
#include <hip/hip_runtime.h>
#include <hip/hip_bf16.h>

#define S_LEN 4096
#define EDIM  300
#define HDIM  512
#define G4    2048
#define NTAG  5
#define NEGV  -10000.0f
#define START_TAG 3
#define STOP_TAG  4
#define L2E 1.4426950408889634f
#define LN2 0.6931471805599453f

// ---------- workspace layout (bytes) ----------
static constexpr size_t OFF_XP    = 0;                                   // bf16 [2][S][2048]
static constexpr size_t XP_BYTES  = (size_t)2 * S_LEN * G4 * 2;
static constexpr size_t OFF_HS    = OFF_XP + XP_BYTES;                   // f32 [2][S][512]
static constexpr size_t HS_BYTES  = (size_t)2 * S_LEN * HDIM * 4;
static constexpr size_t OFF_HBUF  = OFF_HS + HS_BYTES;                   // f32 [2][2][512]
static constexpr size_t HBUF_BYTES= (size_t)2 * 2 * HDIM * 4;
static constexpr size_t OFF_FLAGS = OFF_HBUF + HBUF_BYTES;               // int [2][16]
static constexpr size_t SYNC_BYTES= HBUF_BYTES + 2 * 16 * 4;
static constexpr size_t OFF_FEATS = OFF_HBUF + 8448;                     // f32 [S][5]
static constexpr size_t OFF_MPART = OFF_FEATS + (size_t)S_LEN * NTAG * 4;// f32 [64][25]
static constexpr size_t OFF_GOLD  = OFF_MPART + (size_t)64 * 25 * 4;     // f32 [64]
static constexpr size_t WS_NEEDED = OFF_GOLD + 256;

// ---------- helpers ----------
static __device__ __forceinline__ float fexp_(float x){ return __builtin_amdgcn_exp2f(x * L2E); }
static __device__ __forceinline__ float fsig_(float x){ return __builtin_amdgcn_rcpf(1.0f + fexp_(-x)); }
static __device__ __forceinline__ float ftanh_(float x){ return 1.0f - 2.0f*__builtin_amdgcn_rcpf(fexp_(2.0f*x) + 1.0f); }

// sum over the 16 lanes of a DPP row (butterfly; all lanes get the total)
static __device__ __forceinline__ float dpp_red16(float x){
  int t;
  t = __builtin_amdgcn_update_dpp(0, __float_as_int(x), 0xB1, 0xF, 0xF, true);  x += __int_as_float(t); // quad_perm [1,0,3,2]
  t = __builtin_amdgcn_update_dpp(0, __float_as_int(x), 0x4E, 0xF, 0xF, true);  x += __int_as_float(t); // quad_perm [2,3,0,1]
  t = __builtin_amdgcn_update_dpp(0, __float_as_int(x), 0x140, 0xF, 0xF, true); x += __int_as_float(t); // row_mirror
  t = __builtin_amdgcn_update_dpp(0, __float_as_int(x), 0x141, 0xF, 0xF, true); x += __int_as_float(t); // row_half_mirror
  return x;
}

static __device__ __forceinline__ float lse5(float t0,float t1,float t2,float t3,float t4){
  float m = fmaxf(fmaxf(fmaxf(t0,t1),fmaxf(t2,t3)),t4);
  float s = __builtin_amdgcn_exp2f((t0-m)*L2E) + __builtin_amdgcn_exp2f((t1-m)*L2E)
          + __builtin_amdgcn_exp2f((t2-m)*L2E) + __builtin_amdgcn_exp2f((t3-m)*L2E)
          + __builtin_amdgcn_exp2f((t4-m)*L2E);
  return m + __builtin_amdgcn_logf(s)*LN2;
}

// C[i][j] = LSE_k(cur[i][k] + bv[k][j]); lane layout: lane = i*5+j (lanes 0..24)
static __device__ __forceinline__ float lse_mm(float cur, float bv, int i, int j){
  const float a0=__shfl(cur, i*5+0), a1=__shfl(cur, i*5+1), a2=__shfl(cur, i*5+2),
              a3=__shfl(cur, i*5+3), a4=__shfl(cur, i*5+4);
  const float c0=__shfl(bv, 0+j),  c1=__shfl(bv, 5+j),  c2=__shfl(bv, 10+j),
              c3=__shfl(bv, 15+j), c4=__shfl(bv, 20+j);
  return lse5(a0+c0, a1+c1, a2+c2, a3+c3, a4+c4);
}

// ---------- phase A: xp[dir][s][2048] = emb[sent[s]] @ w_ih.T + (b_ih+b_hh), stored bf16 ----------
__global__ __launch_bounds__(256) void xp_gemm(
    const int* __restrict__ sentence, const float* __restrict__ emb,
    const float* __restrict__ w_ih_f, const float* __restrict__ b_ih_f, const float* __restrict__ b_hh_f,
    const float* __restrict__ w_ih_b, const float* __restrict__ b_ih_b, const float* __restrict__ b_hh_b,
    __hip_bfloat16* __restrict__ xp)
{
  __shared__ float At[32][132];
  __shared__ float Bt[32][132];
  __shared__ int sent_s[128];

  const int dir = blockIdx.y;
  const int tm = blockIdx.x & 31;
  const int tn = blockIdx.x >> 5;
  const float* __restrict__ wih = dir ? w_ih_b : w_ih_f;
  const float* __restrict__ bi  = dir ? b_ih_b : b_ih_f;
  const float* __restrict__ bh  = dir ? b_hh_b : b_hh_f;

  const int tid = threadIdx.x;
  if (tid < 128) sent_s[tid] = sentence[tm*128 + tid];

  const int ty = tid >> 4, tx = tid & 15;
  const int li = tid >> 1, lh = tid & 1;

  float acc[8][8];
#pragma unroll
  for (int i = 0; i < 8; ++i){
#pragma unroll
    for (int j = 0; j < 8; ++j) acc[i][j] = 0.0f;
  }
  __syncthreads();

  for (int kc0 = 0; kc0 < EDIM; kc0 += 32) {
    const int kw = (EDIM - kc0 < 32) ? (EDIM - kc0) : 32;
    if (kc0 + lh*16 + 16 <= EDIM) {
      const float4* pa = (const float4*)(emb + (size_t)sent_s[li]*EDIM + kc0 + lh*16);
      const float4* pb = (const float4*)(wih + (size_t)(tn*128 + li)*EDIM + kc0 + lh*16);
#pragma unroll
      for (int v = 0; v < 4; ++v) {
        const float4 a = pa[v], b = pb[v];
        const int kk = lh*16 + v*4;
        At[kk+0][li] = a.x; At[kk+1][li] = a.y; At[kk+2][li] = a.z; At[kk+3][li] = a.w;
        Bt[kk+0][li] = b.x; Bt[kk+1][li] = b.y; Bt[kk+2][li] = b.z; Bt[kk+3][li] = b.w;
      }
    } else {
#pragma unroll
      for (int jj = 0; jj < 16; ++jj) {
        const int col = kc0 + lh*16 + jj;
        float av = 0.f, bv = 0.f;
        if (col < EDIM) {
          av = emb[(size_t)sent_s[li]*EDIM + col];
          bv = wih[(size_t)(tn*128 + li)*EDIM + col];
        }
        At[lh*16+jj][li] = av;
        Bt[lh*16+jj][li] = bv;
      }
    }
    __syncthreads();
#pragma unroll 4
    for (int k = 0; k < kw; ++k) {
      const float4 a0 = *(const float4*)&At[k][ty*8];
      const float4 a1 = *(const float4*)&At[k][ty*8+4];
      const float4 b0 = *(const float4*)&Bt[k][tx*8];
      const float4 b1 = *(const float4*)&Bt[k][tx*8+4];
      const float av[8] = {a0.x,a0.y,a0.z,a0.w,a1.x,a1.y,a1.z,a1.w};
      const float bv[8] = {b0.x,b0.y,b0.z,b0.w,b1.x,b1.y,b1.z,b1.w};
#pragma unroll
      for (int i = 0; i < 8; ++i){
#pragma unroll
        for (int j = 0; j < 8; ++j) acc[i][j] = __builtin_fmaf(av[i], bv[j], acc[i][j]);
      }
    }
    __syncthreads();
  }

  const int n0 = tn*128 + tx*8;
  float bias[8];
#pragma unroll
  for (int j = 0; j < 8; ++j) bias[j] = bi[n0+j] + bh[n0+j];

  __hip_bfloat16* __restrict__ xpd = xp + (size_t)dir * S_LEN * G4;
#pragma unroll
  for (int i = 0; i < 8; ++i) {
    const int m = tm*128 + ty*8 + i;
    __hip_bfloat16 __align__(16) tmp[8];
#pragma unroll
    for (int j = 0; j < 8; ++j) tmp[j] = __float2bfloat16(acc[i][j] + bias[j]);
    *(uint4*)(xpd + (size_t)m*G4 + n0) = *(const uint4*)tmp;
  }
}

// ---------- phase B: persistent BiLSTM. 16 wgs per direction, weights resident in VGPRs ----------
__global__ __launch_bounds__(512, 2) void lstm_pers(
    const float* __restrict__ w_hh_f, const float* __restrict__ w_hh_b,
    const __hip_bfloat16* __restrict__ xp, float* __restrict__ hs,
    float* __restrict__ hbuf, int* __restrict__ flags)
{
  __shared__ float gsum[128];
  const int dir = blockIdx.x >> 4;
  const int wg  = blockIdx.x & 15;
  const int tid = threadIdx.x;
  const int lane = tid & 63;
  const int q   = tid & 15;   // column chunk 0..15 (cols q*32 .. q*32+32)
  const int rt  = tid >> 4;   // row group 0..31 (local rows rt*4 .. rt*4+4)

  const float* __restrict__ whh = dir ? w_hh_b : w_hh_f;
  const __hip_bfloat16* __restrict__ xpd = xp + (size_t)dir * S_LEN * G4;
  float* __restrict__ hsd = hs + (size_t)dir * S_LEN * HDIM;
  float* __restrict__ hb  = hbuf + dir * 2 * HDIM;
  int*   __restrict__ flg = flags + dir * 16;

  // weight slice: local row lr = rt*4+rr -> global row (lr>>5)*512 + wg*32 + (lr&31)
  float w[4][32];
#pragma unroll
  for (int rr = 0; rr < 4; ++rr) {
    const int lr = rt*4 + rr;
    const int grow = (lr >> 5) * HDIM + wg*32 + (lr & 31);
    const float4* wp = (const float4*)(whh + (size_t)grow * HDIM + q*32);
#pragma unroll
    for (int v = 0; v < 8; ++v) {
      const float4 f = wp[v];
      w[rr][v*4+0] = f.x; w[rr][v*4+1] = f.y; w[rr][v*4+2] = f.z; w[rr][v*4+3] = f.w;
    }
  }

  float cst = 0.0f;                       // cell state (wave0 lanes 0..31 only)
  float xnf0=0.f, xnf1=0.f, xnf2=0.f, xnf3=0.f;
  if (tid < 32) {
    const int t0 = dir ? (S_LEN-1) : 0;
    xnf0 = __bfloat162float(xpd[(size_t)t0*G4 + 0*HDIM + wg*32 + tid]);
    xnf1 = __bfloat162float(xpd[(size_t)t0*G4 + 1*HDIM + wg*32 + tid]);
    xnf2 = __bfloat162float(xpd[(size_t)t0*G4 + 2*HDIM + wg*32 + tid]);
    xnf3 = __bfloat162float(xpd[(size_t)t0*G4 + 3*HDIM + wg*32 + tid]);
  }

#pragma clang loop unroll(disable)
  for (int s = 0; s < S_LEN; ++s) {
    // 1. wait until all 16 wgs of this direction finished step s-1
    if (s > 0) {
      int v = s;
      int spins = 0;
      while (true) {
        if (lane < 16) v = __hip_atomic_load(&flg[lane], __ATOMIC_RELAXED, __HIP_MEMORY_SCOPE_AGENT);
        if (__all(v >= s)) break;
        if (++spins > 1000000) break;     // safety bailout: wrong answer instead of hang
        __builtin_amdgcn_s_sleep(1);
      }
      __threadfence();                    // acquire: make remote h stores visible
    }

    // 2. load h_{s-1} chunk (32 floats) from the parity buffer
    float hv[32];
    {
      const float4* hp = (const float4*)(hb + ((s & 1) ^ 1) * HDIM + q*32);
#pragma unroll
      for (int v = 0; v < 8; ++v) {
        const float4 f = hp[v];
        hv[v*4+0]=f.x; hv[v*4+1]=f.y; hv[v*4+2]=f.z; hv[v*4+3]=f.w;
      }
    }

    // 3. partial matvec: 4 rows x 32 cols
    float a0=0.f, a1=0.f, a2=0.f, a3=0.f;
#pragma unroll
    for (int cc = 0; cc < 32; ++cc) {
      const float h = hv[cc];
      a0 = __builtin_fmaf(w[0][cc], h, a0);
      a1 = __builtin_fmaf(w[1][cc], h, a1);
      a2 = __builtin_fmaf(w[2][cc], h, a2);
      a3 = __builtin_fmaf(w[3][cc], h, a3);
    }
    // 4. reduce across the 16 column chunks (DPP row = exactly the 16 q-lanes of one rt)
    a0 = dpp_red16(a0); a1 = dpp_red16(a1); a2 = dpp_red16(a2); a3 = dpp_red16(a3);
    if (q == 0) *(float4*)&gsum[rt*4] = make_float4(a0, a1, a2, a3);
    __syncthreads();

    // 5. gate assembly + state update on wave0 lanes 0..31 (unit u = tid)
    if (tid < 32) {
      const int tt = dir ? (S_LEN-1-s) : s;
      const float gi = gsum[tid]      + xnf0;
      const float gf = gsum[32 + tid] + xnf1;
      const float gg = gsum[64 + tid] + xnf2;
      const float go = gsum[96 + tid] + xnf3;
      const float iv = fsig_(gi), fv = fsig_(gf), zv = ftanh_(gg), ov = fsig_(go);
      cst = fv*cst + iv*zv;
      const float hval = ov * ftanh_(cst);
      hsd[(size_t)tt*HDIM + wg*32 + tid] = hval;
      hb[(s & 1)*HDIM + wg*32 + tid] = hval;
    }
    if (tid == 0) __hip_atomic_store(&flg[wg], s+1, __ATOMIC_RELEASE, __HIP_MEMORY_SCOPE_AGENT);
    // 6. prefetch next step's xp slice (off the critical flag-publish path)
    if (tid < 32 && s+1 < S_LEN) {
      const int tn_ = dir ? (S_LEN-2-s) : (s+1);
      xnf0 = __bfloat162float(xpd[(size_t)tn_*G4 + 0*HDIM + wg*32 + tid]);
      xnf1 = __bfloat162float(xpd[(size_t)tn_*G4 + 1*HDIM + wg*32 + tid]);
      xnf2 = __bfloat162float(xpd[(size_t)tn_*G4 + 2*HDIM + wg*32 + tid]);
      xnf3 = __bfloat162float(xpd[(size_t)tn_*G4 + 3*HDIM + wg*32 + tid]);
    }
  }
}

// ---------- phase C: feats[s][t] = [hf,hb] . w_tag[t] + b_tag[t] ----------
__global__ __launch_bounds__(64) void feats_ker(
    const float* __restrict__ hs, const float* __restrict__ w_tag,
    const float* __restrict__ b_tag, float* __restrict__ feats)
{
  const int row = blockIdx.x;
  const int l = threadIdx.x;
  const float* __restrict__ hf  = hs + (size_t)row*HDIM;
  const float* __restrict__ hbk = hs + (size_t)S_LEN*HDIM + (size_t)row*HDIM;
  float a0=0,a1=0,a2=0,a3=0,a4=0;
#pragma unroll
  for (int i = 0; i < 8; ++i) {
    const int j = l + i*64;
    const float hfv = hf[j];
    const float hbv = hbk[j];
    a0 += hfv*w_tag[0*1024+j] + hbv*w_tag[0*1024+512+j];
    a1 += hfv*w_tag[1*1024+j] + hbv*w_tag[1*1024+512+j];
    a2 += hfv*w_tag[2*1024+j] + hbv*w_tag[2*1024+512+j];
    a3 += hfv*w_tag[3*1024+j] + hbv*w_tag[3*1024+512+j];
    a4 += hfv*w_tag[4*1024+j] + hbv*w_tag[4*1024+512+j];
  }
#pragma unroll
  for (int off = 32; off; off >>= 1) {
    a0 += __shfl_xor(a0, off); a1 += __shfl_xor(a1, off); a2 += __shfl_xor(a2, off);
    a3 += __shfl_xor(a3, off); a4 += __shfl_xor(a4, off);
  }
  if (l == 0) {
    feats[row*NTAG+0] = a0 + b_tag[0];
    feats[row*NTAG+1] = a1 + b_tag[1];
    feats[row*NTAG+2] = a2 + b_tag[2];
    feats[row*NTAG+3] = a3 + b_tag[3];
    feats[row*NTAG+4] = a4 + b_tag[4];
  }
}

// ---------- phase D: CRF log-partition as a log-semiring 5x5 matrix reduction + gold score ----------
__global__ __launch_bounds__(64) void crf_part(
    const float* __restrict__ feats, const float* __restrict__ trans,
    const int* __restrict__ tags, float* __restrict__ Mpart, float* __restrict__ gold_part)
{
  const int blk = blockIdx.x;         // 64 blocks x 64 steps
  const int l = threadIdx.x;
  const int s0 = blk * 64;
  const bool act = (l < 25);
  const int i = act ? (l/5) : 0;
  const int j = act ? (l%5) : 0;
  const float tT = trans[j*NTAG + i]; // M_s[i][j] = trans[j][i] + feats[s][j]
  float cur = tT + feats[(size_t)s0*NTAG + j];
  for (int s = s0+1; s < s0+64; ++s) {
    const float bv = tT + feats[(size_t)s*NTAG + j];
    cur = lse_mm(cur, bv, i, j);
  }
  if (act) Mpart[blk*25 + l] = cur;

  // gold partial: s = s0 + lane
  const int s = s0 + l;
  const int tg = tags[s];
  const int pv = (s == 0) ? START_TAG : tags[s-1];
  float gv = trans[tg*NTAG + pv] + feats[(size_t)s*NTAG + tg];
#pragma unroll
  for (int off = 32; off; off >>= 1) gv += __shfl_xor(gv, off);
  if (l == 0) gold_part[blk] = gv;
}

__global__ __launch_bounds__(64) void crf_final(
    const float* __restrict__ Mpart, const float* __restrict__ gold_part,
    const float* __restrict__ trans, const int* __restrict__ tags, float* __restrict__ out)
{
  const int l = threadIdx.x;
  const bool act = (l < 25);
  const int i = act ? (l/5) : 0;
  const int j = act ? (l%5) : 0;
  float cur = Mpart[act ? l : 0];
  for (int b = 1; b < 64; ++b) {
    const float bv = Mpart[b*25 + (act ? l : 0)];
    cur = lse_mm(cur, bv, i, j);
  }
  // fold alpha0 (0 at START, NEG elsewhere):  aF[j] = LSE_i(alpha0[i] + P[i][j])
  const float t0 = ((0==START_TAG)?0.f:NEGV) + __shfl(cur, 0*5 + j);
  const float t1 = ((1==START_TAG)?0.f:NEGV) + __shfl(cur, 1*5 + j);
  const float t2 = ((2==START_TAG)?0.f:NEGV) + __shfl(cur, 2*5 + j);
  const float t3 = ((3==START_TAG)?0.f:NEGV) + __shfl(cur, 3*5 + j);
  const float t4 = ((4==START_TAG)?0.f:NEGV) + __shfl(cur, 4*5 + j);
  const float aF = lse5(t0,t1,t2,t3,t4);       // lanes 0..4 hold aF[j=lane]
  const float f0 = __shfl(aF, 0) + trans[STOP_TAG*NTAG + 0];
  const float f1 = __shfl(aF, 1) + trans[STOP_TAG*NTAG + 1];
  const float f2 = __shfl(aF, 2) + trans[STOP_TAG*NTAG + 2];
  const float f3 = __shfl(aF, 3) + trans[STOP_TAG*NTAG + 3];
  const float f4 = __shfl(aF, 4) + trans[STOP_TAG*NTAG + 4];
  const float fwd = lse5(f0,f1,f2,f3,f4);
  float gv = gold_part[l];
#pragma unroll
  for (int off = 32; off; off >>= 1) gv += __shfl_xor(gv, off);
  if (l == 0) out[0] = fwd - (gv + trans[STOP_TAG*NTAG + tags[S_LEN-1]]);
}

// ---------- launcher ----------
extern "C" void kernel_launch(void* const* d_in, const int* in_sizes, int n_in,
                              void* d_out, int out_size, void* d_ws, size_t ws_size,
                              hipStream_t stream) {
  const int*   sentence = (const int*)d_in[0];
  const int*   tags     = (const int*)d_in[1];
  const float* emb      = (const float*)d_in[2];
  const float* w_ih_f   = (const float*)d_in[3];
  const float* w_hh_f   = (const float*)d_in[4];
  const float* b_ih_f   = (const float*)d_in[5];
  const float* b_hh_f   = (const float*)d_in[6];
  const float* w_ih_b   = (const float*)d_in[7];
  const float* w_hh_b   = (const float*)d_in[8];
  const float* b_ih_b   = (const float*)d_in[9];
  const float* b_hh_b   = (const float*)d_in[10];
  const float* w_tag    = (const float*)d_in[11];
  const float* b_tag    = (const float*)d_in[12];
  const float* trans    = (const float*)d_in[13];
  float* out = (float*)d_out;
  char* ws = (char*)d_ws;
  if (ws_size < WS_NEEDED) return;   // clean wrong-answer instead of OOB

  __hip_bfloat16* xp   = (__hip_bfloat16*)(ws + OFF_XP);
  float* hs            = (float*)(ws + OFF_HS);
  float* hbuf          = (float*)(ws + OFF_HBUF);
  int*   flags         = (int*)(ws + OFF_FLAGS);
  float* feats         = (float*)(ws + OFF_FEATS);
  float* Mpart         = (float*)(ws + OFF_MPART);
  float* gold_part     = (float*)(ws + OFF_GOLD);

  hipMemsetAsync(ws + OFF_HBUF, 0, SYNC_BYTES, stream);
  xp_gemm<<<dim3(512, 2, 1), dim3(256), 0, stream>>>(sentence, emb,
      w_ih_f, b_ih_f, b_hh_f, w_ih_b, b_ih_b, b_hh_b, xp);
  lstm_pers<<<dim3(32), dim3(512), 0, stream>>>(w_hh_f, w_hh_b, xp, hs, hbuf, flags);
  feats_ker<<<dim3(4096), dim3(64), 0, stream>>>(hs, w_tag, b_tag, feats);
  crf_part<<<dim3(64), dim3(64), 0, stream>>>(feats, trans, tags, Mpart, gold_part);
  crf_final<<<dim3(1), dim3(64), 0, stream>>>(Mpart, gold_part, trans, tags, out);
}

// Round 2
// 9154.382 us; speedup vs baseline: 3.8857x; 3.8857x over previous
//
#include <hip/hip_runtime.h>
#include <hip/hip_bf16.h>

#define S_LEN 4096
#define EDIM  300
#define HDIM  512
#define G4    2048
#define NTAG  5
#define NEGV  -10000.0f
#define START_TAG 3
#define STOP_TAG  4
#define L2E 1.4426950408889634f
#define LN2 0.6931471805599453f
#define POIS_U 0x7F7F7F7Fu

typedef __attribute__((ext_vector_type(4))) float f32x4;

// ---------- workspace layout (bytes) ----------
static constexpr size_t OFF_XP    = 0;                                   // bf16 [2][S][2048]
static constexpr size_t XP_BYTES  = (size_t)2 * S_LEN * G4 * 2;
static constexpr size_t OFF_HBS   = OFF_XP + XP_BYTES;                   // f32 [2][S][512] poison-polled h history
static constexpr size_t HBS_BYTES = (size_t)2 * S_LEN * HDIM * 4;
static constexpr size_t OFF_FEATS = OFF_HBS + HBS_BYTES;                 // f32 [S][5]
static constexpr size_t OFF_MPART = OFF_FEATS + (size_t)S_LEN * NTAG * 4;// f32 [64][25]
static constexpr size_t OFF_GOLD  = OFF_MPART + (size_t)64 * 25 * 4;     // f32 [64]
static constexpr size_t WS_NEEDED = OFF_GOLD + 256;

// ---------- helpers ----------
static __device__ __forceinline__ float fexp_(float x){ return __builtin_amdgcn_exp2f(x * L2E); }
static __device__ __forceinline__ float fsig_(float x){ return __builtin_amdgcn_rcpf(1.0f + fexp_(-x)); }
static __device__ __forceinline__ float ftanh_(float x){ return 1.0f - 2.0f*__builtin_amdgcn_rcpf(fexp_(2.0f*x) + 1.0f); }

static __device__ __forceinline__ float lse5(float t0,float t1,float t2,float t3,float t4){
  float m = fmaxf(fmaxf(fmaxf(t0,t1),fmaxf(t2,t3)),t4);
  float s = __builtin_amdgcn_exp2f((t0-m)*L2E) + __builtin_amdgcn_exp2f((t1-m)*L2E)
          + __builtin_amdgcn_exp2f((t2-m)*L2E) + __builtin_amdgcn_exp2f((t3-m)*L2E)
          + __builtin_amdgcn_exp2f((t4-m)*L2E);
  return m + __builtin_amdgcn_logf(s)*LN2;
}

// C[i][j] = LSE_k(cur[i][k] + bv[k][j]); lane layout: lane = i*5+j (lanes 0..24)
static __device__ __forceinline__ float lse_mm(float cur, float bv, int i, int j){
  const float a0=__shfl(cur, i*5+0), a1=__shfl(cur, i*5+1), a2=__shfl(cur, i*5+2),
              a3=__shfl(cur, i*5+3), a4=__shfl(cur, i*5+4);
  const float c0=__shfl(bv, 0+j),  c1=__shfl(bv, 5+j),  c2=__shfl(bv, 10+j),
              c3=__shfl(bv, 15+j), c4=__shfl(bv, 20+j);
  return lse5(a0+c0, a1+c1, a2+c2, a3+c3, a4+c4);
}

// ---------- phase 0: poison-fill hbs with coherent (sc0 sc1) stores so no dirty L2 lines exist ----------
__global__ __launch_bounds__(256) void fill_poison(float* __restrict__ p, int n4){
  const int idx = blockIdx.x*blockDim.x + threadIdx.x;
  const int stride = gridDim.x*blockDim.x;
  f32x4 pv;
  pv.x = __uint_as_float(POIS_U); pv.y = __uint_as_float(POIS_U);
  pv.z = __uint_as_float(POIS_U); pv.w = __uint_as_float(POIS_U);
  for (int i = idx; i < n4; i += stride) {
    float* dst = p + (size_t)i*4;
    asm volatile("global_store_dwordx4 %0, %1, off sc0 sc1" :: "v"(dst), "v"(pv) : "memory");
  }
}

// ---------- phase A: xp[dir][s][2048] = emb[sent[s]] @ w_ih.T + (b_ih+b_hh), stored bf16 ----------
__global__ __launch_bounds__(256) void xp_gemm(
    const int* __restrict__ sentence, const float* __restrict__ emb,
    const float* __restrict__ w_ih_f, const float* __restrict__ b_ih_f, const float* __restrict__ b_hh_f,
    const float* __restrict__ w_ih_b, const float* __restrict__ b_ih_b, const float* __restrict__ b_hh_b,
    __hip_bfloat16* __restrict__ xp)
{
  __shared__ float At[32][132];
  __shared__ float Bt[32][132];
  __shared__ int sent_s[128];

  const int dir = blockIdx.y;
  const int tm = blockIdx.x & 31;
  const int tn = blockIdx.x >> 5;
  const float* __restrict__ wih = dir ? w_ih_b : w_ih_f;
  const float* __restrict__ bi  = dir ? b_ih_b : b_ih_f;
  const float* __restrict__ bh  = dir ? b_hh_b : b_hh_f;

  const int tid = threadIdx.x;
  if (tid < 128) sent_s[tid] = sentence[tm*128 + tid];

  const int ty = tid >> 4, tx = tid & 15;
  const int li = tid >> 1, lh = tid & 1;

  float acc[8][8];
#pragma unroll
  for (int i = 0; i < 8; ++i){
#pragma unroll
    for (int j = 0; j < 8; ++j) acc[i][j] = 0.0f;
  }
  __syncthreads();

  for (int kc0 = 0; kc0 < EDIM; kc0 += 32) {
    const int kw = (EDIM - kc0 < 32) ? (EDIM - kc0) : 32;
    if (kc0 + lh*16 + 16 <= EDIM) {
      const float4* pa = (const float4*)(emb + (size_t)sent_s[li]*EDIM + kc0 + lh*16);
      const float4* pb = (const float4*)(wih + (size_t)(tn*128 + li)*EDIM + kc0 + lh*16);
#pragma unroll
      for (int v = 0; v < 4; ++v) {
        const float4 a = pa[v], b = pb[v];
        const int kk = lh*16 + v*4;
        At[kk+0][li] = a.x; At[kk+1][li] = a.y; At[kk+2][li] = a.z; At[kk+3][li] = a.w;
        Bt[kk+0][li] = b.x; Bt[kk+1][li] = b.y; Bt[kk+2][li] = b.z; Bt[kk+3][li] = b.w;
      }
    } else {
#pragma unroll
      for (int jj = 0; jj < 16; ++jj) {
        const int col = kc0 + lh*16 + jj;
        float av = 0.f, bv = 0.f;
        if (col < EDIM) {
          av = emb[(size_t)sent_s[li]*EDIM + col];
          bv = wih[(size_t)(tn*128 + li)*EDIM + col];
        }
        At[lh*16+jj][li] = av;
        Bt[lh*16+jj][li] = bv;
      }
    }
    __syncthreads();
#pragma unroll 4
    for (int k = 0; k < kw; ++k) {
      const float4 a0 = *(const float4*)&At[k][ty*8];
      const float4 a1 = *(const float4*)&At[k][ty*8+4];
      const float4 b0 = *(const float4*)&Bt[k][tx*8];
      const float4 b1 = *(const float4*)&Bt[k][tx*8+4];
      const float av[8] = {a0.x,a0.y,a0.z,a0.w,a1.x,a1.y,a1.z,a1.w};
      const float bv[8] = {b0.x,b0.y,b0.z,b0.w,b1.x,b1.y,b1.z,b1.w};
#pragma unroll
      for (int i = 0; i < 8; ++i){
#pragma unroll
        for (int j = 0; j < 8; ++j) acc[i][j] = __builtin_fmaf(av[i], bv[j], acc[i][j]);
      }
    }
    __syncthreads();
  }

  const int n0 = tn*128 + tx*8;
  float bias[8];
#pragma unroll
  for (int j = 0; j < 8; ++j) bias[j] = bi[n0+j] + bh[n0+j];

  __hip_bfloat16* __restrict__ xpd = xp + (size_t)dir * S_LEN * G4;
#pragma unroll
  for (int i = 0; i < 8; ++i) {
    const int m = tm*128 + ty*8 + i;
    __hip_bfloat16 __align__(16) tmp[8];
#pragma unroll
    for (int j = 0; j < 8; ++j) tmp[j] = __float2bfloat16(acc[i][j] + bias[j]);
    *(uint4*)(xpd + (size_t)m*G4 + n0) = *(const uint4*)tmp;
  }
}

// ---------- phase B: persistent BiLSTM, poison-poll sync, weights in VGPRs ----------
// 16 wgs/dir x 512 threads. Wave w_ owns units [wg*32+w_*4, +4); lane l owns h-cols [8l, 8l+8).
// No __syncthreads, no flags, no fences: h values self-signal via poison pattern.
__global__ __launch_bounds__(512, 1) void lstm_pers(
    const float* __restrict__ w_hh_f, const float* __restrict__ w_hh_b,
    const __hip_bfloat16* __restrict__ xp, float* __restrict__ hbs)
{
  const int dir = blockIdx.x >> 4;
  const int wg  = blockIdx.x & 15;
  const int tid = threadIdx.x;
  const int w_  = tid >> 6;
  const int l   = tid & 63;
  const int u   = l & 3;                 // unit tracked by this lane's gate path (lanes 0-3 are owners)
  const int gu  = wg*32 + w_*4 + u;      // global unit index

  const float* __restrict__ whh = dir ? w_hh_b : w_hh_f;
  const __hip_bfloat16* __restrict__ xpd = xp + (size_t)dir * S_LEN * G4;
  float* __restrict__ hbs_d = hbs + (size_t)dir * S_LEN * HDIM;

  // resident weights: 16 rows (4 units x 4 gates) x 8 cols. r = 4*u_loc + g.
  float w[16][8];
#pragma unroll
  for (int r = 0; r < 16; ++r) {
    const int g = r & 3, ul = r >> 2;
    const int grow = g*HDIM + wg*32 + w_*4 + ul;
    const float4* wp = (const float4*)(whh + (size_t)grow*HDIM + l*8);
    const float4 w0 = wp[0], w1 = wp[1];
    w[r][0]=w0.x; w[r][1]=w0.y; w[r][2]=w0.z; w[r][3]=w0.w;
    w[r][4]=w1.x; w[r][5]=w1.y; w[r][6]=w1.z; w[r][7]=w1.w;
  }

  // gather lane for row r=4u+g sits at lane (u>>1) + 2*(u&1) + 4*(g>>1) + 8*(g&1)
  const int f_ = 2*(l&1) + ((l>>1)&1);

  const __hip_bfloat16* xptr = xpd + (size_t)(dir ? (S_LEN-1) : 0) * G4 + gu;
  const ptrdiff_t xstep = dir ? -(ptrdiff_t)G4 : (ptrdiff_t)G4;
  float xn0 = __bfloat162float(xptr[0*HDIM]);
  float xn1 = __bfloat162float(xptr[1*HDIM]);
  float xn2 = __bfloat162float(xptr[2*HDIM]);
  float xn3 = __bfloat162float(xptr[3*HDIM]);

  const float* psrc = hbs_d + l*8;
  float*       pdst = hbs_d + gu;
  float cst = 0.0f;

#pragma clang loop unroll(disable)
  for (int s = 0; s < S_LEN; ++s) {
    float acc[16];
    if (s == 0) {
#pragma unroll
      for (int r = 0; r < 16; ++r) acc[r] = 0.0f;
    } else {
      f32x4 pa, pb;
      const float* sp = psrc + (size_t)(s-1)*HDIM;
      for (int it = 0; it < (1<<18); ++it) {
        asm volatile(
          "global_load_dwordx4 %0, %2, off sc0 sc1\n\t"
          "global_load_dwordx4 %1, %2, off offset:16 sc0 sc1\n\t"
          "s_waitcnt vmcnt(0)"
          : "=&v"(pa), "=&v"(pb) : "v"(sp) : "memory");
        const int ok = (__float_as_uint(pa.x) != POIS_U) & (__float_as_uint(pa.y) != POIS_U)
                     & (__float_as_uint(pa.z) != POIS_U) & (__float_as_uint(pa.w) != POIS_U)
                     & (__float_as_uint(pb.x) != POIS_U) & (__float_as_uint(pb.y) != POIS_U)
                     & (__float_as_uint(pb.z) != POIS_U) & (__float_as_uint(pb.w) != POIS_U);
        if (__all(ok)) break;
      }
      const float h0=pa.x,h1=pa.y,h2=pa.z,h3=pa.w,h4=pb.x,h5=pb.y,h6=pb.z,h7=pb.w;
#pragma unroll
      for (int r = 0; r < 16; ++r) {
        float a =            w[r][0]*h0;
        a = __builtin_fmaf(w[r][1],h1,a); a = __builtin_fmaf(w[r][2],h2,a);
        a = __builtin_fmaf(w[r][3],h3,a); a = __builtin_fmaf(w[r][4],h4,a);
        a = __builtin_fmaf(w[r][5],h5,a); a = __builtin_fmaf(w[r][6],h6,a);
        a = __builtin_fmaf(w[r][7],h7,a);
        acc[r] = a;
      }
    }

    // reduce-scatter: 16 row-partials over 64 lanes -> lane holds one row total
#pragma unroll
    for (int k = 0; k < 4; ++k) {
      const int m = 1 << k;
      const int half = 8 >> k;
      const bool up = (l & m) != 0;
#pragma unroll
      for (int t = 0; t < half; ++t) {
        const float mine = up ? acc[half+t] : acc[t];
        const float send = up ? acc[t] : acc[half+t];
        acc[t] = mine + __shfl_xor(send, m);
      }
    }
    float tot = acc[0];
    tot += __shfl_xor(tot, 16);
    tot += __shfl_xor(tot, 32);

    // gates for unit u = l&3 (all lanes compute redundantly; lanes 0-3 are canonical)
    const float gi = __shfl(tot, f_ + 0)  + xn0;
    const float gf = __shfl(tot, f_ + 8)  + xn1;
    const float gg = __shfl(tot, f_ + 4)  + xn2;
    const float go = __shfl(tot, f_ + 12) + xn3;
    const float iv = fsig_(gi), fv = fsig_(gf), zv = ftanh_(gg), ov = fsig_(go);
    cst = fv*cst + iv*zv;
    const float hval = ov * ftanh_(cst);
    if (l < 4) {
      float* dp = pdst + (size_t)s*HDIM;
      asm volatile("global_store_dword %0, %1, off sc0 sc1" :: "v"(dp), "v"(hval) : "memory");
    }
    if (s+1 < S_LEN) {
      xptr += xstep;
      xn0 = __bfloat162float(xptr[0*HDIM]);
      xn1 = __bfloat162float(xptr[1*HDIM]);
      xn2 = __bfloat162float(xptr[2*HDIM]);
      xn3 = __bfloat162float(xptr[3*HDIM]);
    }
  }
}

// ---------- phase C: feats[s][t] = [hf,hb] . w_tag[t] + b_tag[t] ----------
// forward h_t = hbs[0][t]; backward h_t = hbs[1][S-1-t]
__global__ __launch_bounds__(64) void feats_ker(
    const float* __restrict__ hbs, const float* __restrict__ w_tag,
    const float* __restrict__ b_tag, float* __restrict__ feats)
{
  const int row = blockIdx.x;
  const int l = threadIdx.x;
  const float* __restrict__ hf  = hbs + (size_t)row*HDIM;
  const float* __restrict__ hbk = hbs + (size_t)S_LEN*HDIM + (size_t)(S_LEN-1-row)*HDIM;
  float a0=0,a1=0,a2=0,a3=0,a4=0;
#pragma unroll
  for (int i = 0; i < 8; ++i) {
    const int j = l + i*64;
    const float hfv = hf[j];
    const float hbv = hbk[j];
    a0 += hfv*w_tag[0*1024+j] + hbv*w_tag[0*1024+512+j];
    a1 += hfv*w_tag[1*1024+j] + hbv*w_tag[1*1024+512+j];
    a2 += hfv*w_tag[2*1024+j] + hbv*w_tag[2*1024+512+j];
    a3 += hfv*w_tag[3*1024+j] + hbv*w_tag[3*1024+512+j];
    a4 += hfv*w_tag[4*1024+j] + hbv*w_tag[4*1024+512+j];
  }
#pragma unroll
  for (int off = 32; off; off >>= 1) {
    a0 += __shfl_xor(a0, off); a1 += __shfl_xor(a1, off); a2 += __shfl_xor(a2, off);
    a3 += __shfl_xor(a3, off); a4 += __shfl_xor(a4, off);
  }
  if (l == 0) {
    feats[row*NTAG+0] = a0 + b_tag[0];
    feats[row*NTAG+1] = a1 + b_tag[1];
    feats[row*NTAG+2] = a2 + b_tag[2];
    feats[row*NTAG+3] = a3 + b_tag[3];
    feats[row*NTAG+4] = a4 + b_tag[4];
  }
}

// ---------- phase D: CRF log-partition as a log-semiring 5x5 matrix reduction + gold score ----------
__global__ __launch_bounds__(64) void crf_part(
    const float* __restrict__ feats, const float* __restrict__ trans,
    const int* __restrict__ tags, float* __restrict__ Mpart, float* __restrict__ gold_part)
{
  const int blk = blockIdx.x;         // 64 blocks x 64 steps
  const int l = threadIdx.x;
  const int s0 = blk * 64;
  const bool act = (l < 25);
  const int i = act ? (l/5) : 0;
  const int j = act ? (l%5) : 0;
  const float tT = trans[j*NTAG + i]; // M_s[i][j] = trans[j][i] + feats[s][j]
  float cur = tT + feats[(size_t)s0*NTAG + j];
  for (int s = s0+1; s < s0+64; ++s) {
    const float bv = tT + feats[(size_t)s*NTAG + j];
    cur = lse_mm(cur, bv, i, j);
  }
  if (act) Mpart[blk*25 + l] = cur;

  // gold partial: s = s0 + lane
  const int s = s0 + l;
  const int tg = tags[s];
  const int pv = (s == 0) ? START_TAG : tags[s-1];
  float gv = trans[tg*NTAG + pv] + feats[(size_t)s*NTAG + tg];
#pragma unroll
  for (int off = 32; off; off >>= 1) gv += __shfl_xor(gv, off);
  if (l == 0) gold_part[blk] = gv;
}

__global__ __launch_bounds__(64) void crf_final(
    const float* __restrict__ Mpart, const float* __restrict__ gold_part,
    const float* __restrict__ trans, const int* __restrict__ tags, float* __restrict__ out)
{
  const int l = threadIdx.x;
  const bool act = (l < 25);
  const int i = act ? (l/5) : 0;
  const int j = act ? (l%5) : 0;
  float cur = Mpart[act ? l : 0];
  for (int b = 1; b < 64; ++b) {
    const float bv = Mpart[b*25 + (act ? l : 0)];
    cur = lse_mm(cur, bv, i, j);
  }
  // fold alpha0 (0 at START, NEG elsewhere):  aF[j] = LSE_i(alpha0[i] + P[i][j])
  const float t0 = ((0==START_TAG)?0.f:NEGV) + __shfl(cur, 0*5 + j);
  const float t1 = ((1==START_TAG)?0.f:NEGV) + __shfl(cur, 1*5 + j);
  const float t2 = ((2==START_TAG)?0.f:NEGV) + __shfl(cur, 2*5 + j);
  const float t3 = ((3==START_TAG)?0.f:NEGV) + __shfl(cur, 3*5 + j);
  const float t4 = ((4==START_TAG)?0.f:NEGV) + __shfl(cur, 4*5 + j);
  const float aF = lse5(t0,t1,t2,t3,t4);       // lanes 0..4 hold aF[j=lane]
  const float f0 = __shfl(aF, 0) + trans[STOP_TAG*NTAG + 0];
  const float f1 = __shfl(aF, 1) + trans[STOP_TAG*NTAG + 1];
  const float f2 = __shfl(aF, 2) + trans[STOP_TAG*NTAG + 2];
  const float f3 = __shfl(aF, 3) + trans[STOP_TAG*NTAG + 3];
  const float f4 = __shfl(aF, 4) + trans[STOP_TAG*NTAG + 4];
  const float fwd = lse5(f0,f1,f2,f3,f4);
  float gv = gold_part[l];
#pragma unroll
  for (int off = 32; off; off >>= 1) gv += __shfl_xor(gv, off);
  if (l == 0) out[0] = fwd - (gv + trans[STOP_TAG*NTAG + tags[S_LEN-1]]);
}

// ---------- launcher ----------
extern "C" void kernel_launch(void* const* d_in, const int* in_sizes, int n_in,
                              void* d_out, int out_size, void* d_ws, size_t ws_size,
                              hipStream_t stream) {
  const int*   sentence = (const int*)d_in[0];
  const int*   tags     = (const int*)d_in[1];
  const float* emb      = (const float*)d_in[2];
  const float* w_ih_f   = (const float*)d_in[3];
  const float* w_hh_f   = (const float*)d_in[4];
  const float* b_ih_f   = (const float*)d_in[5];
  const float* b_hh_f   = (const float*)d_in[6];
  const float* w_ih_b   = (const float*)d_in[7];
  const float* w_hh_b   = (const float*)d_in[8];
  const float* b_ih_b   = (const float*)d_in[9];
  const float* b_hh_b   = (const float*)d_in[10];
  const float* w_tag    = (const float*)d_in[11];
  const float* b_tag    = (const float*)d_in[12];
  const float* trans    = (const float*)d_in[13];
  float* out = (float*)d_out;
  char* ws = (char*)d_ws;
  if (ws_size < WS_NEEDED) return;   // clean wrong-answer instead of OOB

  __hip_bfloat16* xp   = (__hip_bfloat16*)(ws + OFF_XP);
  float* hbs           = (float*)(ws + OFF_HBS);
  float* feats         = (float*)(ws + OFF_FEATS);
  float* Mpart         = (float*)(ws + OFF_MPART);
  float* gold_part     = (float*)(ws + OFF_GOLD);

  const int n4 = (2 * S_LEN * HDIM) / 4;
  fill_poison<<<dim3(1024), dim3(256), 0, stream>>>(hbs, n4);
  xp_gemm<<<dim3(512, 2, 1), dim3(256), 0, stream>>>(sentence, emb,
      w_ih_f, b_ih_f, b_hh_f, w_ih_b, b_ih_b, b_hh_b, xp);
  lstm_pers<<<dim3(32), dim3(512), 0, stream>>>(w_hh_f, w_hh_b, xp, hbs);
  feats_ker<<<dim3(4096), dim3(64), 0, stream>>>(hbs, w_tag, b_tag, feats);
  crf_part<<<dim3(64), dim3(64), 0, stream>>>(feats, trans, tags, Mpart, gold_part);
  crf_final<<<dim3(1), dim3(64), 0, stream>>>(Mpart, gold_part, trans, tags, out);
}